// Round 1
// baseline (31.297 us; speedup 1.0000x reference)
//
#include <hip/hip_runtime.h>

// Problem constants
constexpr int Bv   = 4;
constexpr int Lv   = 4096;
constexpr int Dv   = 128;   // hidden
constexpr int Av   = 16;    // atten_size
constexpr int Wwin = 2*Av + 1; // 33
constexpr int OUTv = 2;
constexpr int HIDv = 24;    // HID_FC
constexpr int NROWS = Bv * Lv; // 16384

// ---------------------------------------------------------------------------
// Wf = Wv_w (128x128) @ fc2_w (128x24)  -> 128x24
// grid: 24 blocks (one per output column), 128 threads (one per output row)
__global__ __launch_bounds__(128) void k_fusew(const float* __restrict__ Wv,
                                               const float* __restrict__ fc2,
                                               float* __restrict__ Wf) {
    const int c = blockIdx.x;   // 0..23
    const int r = threadIdx.x;  // 0..127
    float acc = 0.f;
#pragma unroll 8
    for (int k = 0; k < Dv; ++k)
        acc = fmaf(Wv[r*Dv + k], fc2[k*HIDv + c], acc);
    Wf[r*HIDv + c] = acc;
}

// ---------------------------------------------------------------------------
// m = relu(x @ W1 + b1) @ Wf     (per 64-row tile)
// grid: NROWS/64 = 256 blocks, 256 threads
// LDS: W1 64KB + Wf 12KB + b1 0.5KB + x-tile 33.8KB  (~110KB, 1 block/CU)
__global__ __launch_bounds__(256) void k_main(const float* __restrict__ x,
                                              const float* __restrict__ W1,
                                              const float* __restrict__ b1,
                                              const float* __restrict__ Wf,
                                              float* __restrict__ m) {
    __shared__ float sW1[Dv * Dv];       // sW1[k*128 + c]
    __shared__ float sWf[Dv * HIDv];     // sWf[k*24 + c]
    __shared__ float sb1[Dv];
    __shared__ float sx[64 * 132];       // padded rows (132) to kill bank conflicts

    const int t  = threadIdx.x;
    const int r0 = blockIdx.x * 64;

    // stage weights (vectorized)
    {
        const float4* src = (const float4*)W1;
        float4* dst = (float4*)sW1;
        for (int i = t; i < Dv*Dv/4; i += 256) dst[i] = src[i];
    }
    {
        const float4* src = (const float4*)Wf;
        float4* dst = (float4*)sWf;
        for (int i = t; i < Dv*HIDv/4; i += 256) dst[i] = src[i];
    }
    if (t < Dv) sb1[t] = b1[t];

    // stage x tile: 64 rows x 128 cols, row pitch 132 floats
    for (int i = t; i < 64 * 32; i += 256) {
        const int r  = i >> 5;     // 32 float4 per row
        const int c4 = i & 31;
        float4 v = ((const float4*)(x + (size_t)(r0 + r) * Dv))[c4];
        *((float4*)(sx + r*132) + c4) = v;
    }
    __syncthreads();

    // register tile: thread (ty,tx) -> rows {ty+16i}, cols {tx*8 .. tx*8+7}
    const int ty = t >> 4;   // 0..15
    const int tx = t & 15;   // 0..15

    float acc[4][8];
#pragma unroll
    for (int i = 0; i < 4; ++i)
#pragma unroll
        for (int j = 0; j < 8; ++j) acc[i][j] = 0.f;

    for (int k4 = 0; k4 < Dv; k4 += 4) {
        float4 av[4];
#pragma unroll
        for (int i = 0; i < 4; ++i)
            av[i] = *(const float4*)&sx[(ty + 16*i)*132 + k4];
#pragma unroll
        for (int kk = 0; kk < 4; ++kk) {
            const int k = k4 + kk;
            const float4 w0 = *(const float4*)&sW1[k*Dv + tx*8];
            const float4 w1 = *(const float4*)&sW1[k*Dv + tx*8 + 4];
#pragma unroll
            for (int i = 0; i < 4; ++i) {
                const float a = ((const float*)(av + i))[kk];
                acc[i][0] = fmaf(a, w0.x, acc[i][0]);
                acc[i][1] = fmaf(a, w0.y, acc[i][1]);
                acc[i][2] = fmaf(a, w0.z, acc[i][2]);
                acc[i][3] = fmaf(a, w0.w, acc[i][3]);
                acc[i][4] = fmaf(a, w1.x, acc[i][4]);
                acc[i][5] = fmaf(a, w1.y, acc[i][5]);
                acc[i][6] = fmaf(a, w1.z, acc[i][6]);
                acc[i][7] = fmaf(a, w1.w, acc[i][7]);
            }
        }
    }

    __syncthreads();   // done reading x from sx; reuse it for h1

    // h1 = relu(acc + b1) -> back into sx
#pragma unroll
    for (int i = 0; i < 4; ++i) {
        const int r = ty + 16*i;
#pragma unroll
        for (int j = 0; j < 8; ++j) {
            const int c = tx*8 + j;
            const float h = acc[i][j] + sb1[c];
            sx[r*132 + c] = h > 0.f ? h : 0.f;
        }
    }
    __syncthreads();

    // m_tile(64x24) = h1(64x128) @ Wf(128x24); write as float4 (24 = 6xfloat4)
    for (int o = t; o < 64 * 6; o += 256) {
        const int r = o / 6;
        const int q = o % 6;
        float4 a4 = {0.f, 0.f, 0.f, 0.f};
#pragma unroll 8
        for (int k = 0; k < Dv; ++k) {
            const float h = sx[r*132 + k];
            const float4 w = *(const float4*)&sWf[k*HIDv + q*4];
            a4.x = fmaf(h, w.x, a4.x);
            a4.y = fmaf(h, w.y, a4.y);
            a4.z = fmaf(h, w.z, a4.z);
            a4.w = fmaf(h, w.w, a4.w);
        }
        *(float4*)&m[(size_t)(r0 + r)*HIDv + q*4] = a4;
    }
}

// ---------------------------------------------------------------------------
// out = relu(slidesum_33(m) + fc2_b) @ fc3 + fc3_b ;  also fill a-region = 1.0
// grid: dim3(Lv/64, Bv) = (64,4), 256 threads
__global__ __launch_bounds__(256) void k_tail(const float* __restrict__ m,
                                              const float* __restrict__ fc2_b,
                                              const float* __restrict__ fc3_w,
                                              const float* __restrict__ fc3_b,
                                              float* __restrict__ out,
                                              float* __restrict__ aout) {
    constexpr int TILE = 64;
    __shared__ float sm[(TILE + 2*Av) * HIDv];  // 96*24
    __shared__ float sh2[TILE * HIDv];          // 64*24

    const int t  = threadIdx.x;
    const int b  = blockIdx.y;
    const int l0 = blockIdx.x * TILE;
    const float* mb = m + (size_t)b * Lv * HIDv;

    // load 96 rows (l0-16 .. l0+79), zero outside [0,Lv)
    for (int i = t; i < (TILE + 2*Av) * 6; i += 256) {
        const int r = i / 6;
        const int q = i % 6;
        const int l = l0 - Av + r;
        float4 v = {0.f, 0.f, 0.f, 0.f};
        if (l >= 0 && l < Lv)
            v = *(const float4*)&mb[(size_t)l*HIDv + q*4];
        *(float4*)&sm[r*HIDv + q*4] = v;
    }
    __syncthreads();

    // sliding 33-sum + bias + relu
    for (int i = t; i < TILE * HIDv; i += 256) {
        const int r = i / HIDv;
        const int c = i % HIDv;
        float s = 0.f;
#pragma unroll
        for (int w = 0; w < Wwin; ++w) s += sm[(r + w)*HIDv + c];
        s += fc2_b[c];
        sh2[i] = s > 0.f ? s : 0.f;
    }
    __syncthreads();

    // fc3: (64 x 24) @ (24 x 2)
    for (int i = t; i < TILE * OUTv; i += 256) {
        const int r  = i / OUTv;
        const int oc = i % OUTv;
        float acc = fc3_b[oc];
#pragma unroll
        for (int c = 0; c < HIDv; ++c)
            acc = fmaf(sh2[r*HIDv + c], fc3_w[c*OUTv + oc], acc);
        out[((size_t)b*Lv + l0 + r)*OUTv + oc] = acc;
    }

    // fill attention-weights output with exactly 1.0 (softmax over size-1 axis)
    {
        float4* a4 = (float4*)aout;
        const int n4 = NROWS * Wwin / 4;             // 135168
        const int nblk = gridDim.x * gridDim.y;      // 256
        const int blk = blockIdx.y * gridDim.x + blockIdx.x;
        const float4 one4 = {1.f, 1.f, 1.f, 1.f};
        for (int i = blk*256 + t; i < n4; i += nblk*256)
            a4[i] = one4;
    }
}

// ---------------------------------------------------------------------------
extern "C" void kernel_launch(void* const* d_in, const int* in_sizes, int n_in,
                              void* d_out, int out_size, void* d_ws, size_t ws_size,
                              hipStream_t stream) {
    const float* x     = (const float*)d_in[0];
    const float* fc1_w = (const float*)d_in[1];
    const float* fc1_b = (const float*)d_in[2];
    // d_in[3] = Wq_w, d_in[4] = Wk_w : dead (softmax over singleton axis)
    const float* Wv_w  = (const float*)d_in[5];
    const float* fc2_w = (const float*)d_in[6];
    const float* fc2_b = (const float*)d_in[7];
    const float* fc3_w = (const float*)d_in[8];
    const float* fc3_b = (const float*)d_in[9];

    float* out  = (float*)d_out;                    // (B,L,2)   32768 floats
    float* aout = (float*)d_out + NROWS * OUTv;     // (B,L,1,33) 540672 floats

    float* Wf = (float*)d_ws;                       // 128*24
    float* m  = (float*)d_ws + 4096;                // NROWS*24

    k_fusew<<<dim3(HIDv), dim3(128), 0, stream>>>(Wv_w, fc2_w, Wf);
    k_main<<<dim3(NROWS/64), dim3(256), 0, stream>>>(x, fc1_w, fc1_b, Wf, m);
    k_tail<<<dim3(Lv/64, Bv), dim3(256), 0, stream>>>(m, fc2_b, fc3_w, fc3_b, out, aout);
}

// Round 2
// 20.343 us; speedup vs baseline: 1.5384x; 1.5384x over previous
//
#include <hip/hip_runtime.h>

// Problem constants
constexpr int Bv   = 4;
constexpr int Lv   = 4096;
constexpr int Dv   = 128;
constexpr int Av   = 16;
constexpr int Wwin = 2*Av + 1;  // 33
constexpr int OUTv = 2;
constexpr int HIDv = 24;
constexpr int NROWS = Bv * Lv;  // 16384

typedef __attribute__((ext_vector_type(8))) short short8;   // 8 bf16 (4 VGPR)
typedef __attribute__((ext_vector_type(4))) short short4v;  // 4 bf16 (8B)
typedef __attribute__((ext_vector_type(4))) float f32x4;    // MFMA acc

__device__ __forceinline__ short f2bf(float f) {  // RNE fp32->bf16
    unsigned u = __builtin_bit_cast(unsigned, f);
    u += 0x7FFFu + ((u >> 16) & 1u);
    return (short)(u >> 16);
}

// ---------------------------------------------------------------------------
// Prep: W1T[n][k] = fc1_w[k][n] as bf16 (128x128), and
//       WfT[n][k] = sum_j Wv[k][j]*fc2[j][n] as bf16 (32x128, rows 24..31 = 0)
// grid 32 x 256 threads: blocks 0..15 transpose, 16..31 WfT
__global__ __launch_bounds__(256) void k_prep(const float* __restrict__ W1,
                                              const float* __restrict__ Wv,
                                              const float* __restrict__ fc2,
                                              short* __restrict__ W1T,
                                              short* __restrict__ WfT) {
    const int b = blockIdx.x, t = threadIdx.x;
    if (b < 16) {
        __shared__ float st[32][36];
        const int bi = b >> 2, bj = b & 3;      // tile (k-block, n-block)
        const int r = t >> 3, q = t & 7;
        const float4 v = *(const float4*)&W1[(size_t)(bi*32 + r)*Dv + bj*32 + q*4];
        st[r][q*4+0] = v.x; st[r][q*4+1] = v.y; st[r][q*4+2] = v.z; st[r][q*4+3] = v.w;
        __syncthreads();
        short4v o;
        o[0] = f2bf(st[q*4+0][r]);
        o[1] = f2bf(st[q*4+1][r]);
        o[2] = f2bf(st[q*4+2][r]);
        o[3] = f2bf(st[q*4+3][r]);
        *(short4v*)&W1T[(size_t)(bj*32 + r)*Dv + bi*32 + q*4] = o;
    } else {
        const int i = (b - 16)*256 + t;         // 0..4095
        const int n = i >> 7, k = i & 127;
        float acc = 0.f;
        if (n < HIDv) {
#pragma unroll 8
            for (int j = 0; j < Dv; ++j)
                acc = fmaf(Wv[(size_t)k*Dv + j], fc2[(size_t)j*HIDv + n], acc);
        }
        WfT[(size_t)n*Dv + k] = f2bf(acc);
    }
}

// ---------------------------------------------------------------------------
// Fused: per block = 64 output rows (+16 halo each side)
//   h1 = relu(x@W1+b1) via MFMA (96 rows), m = h1@Wf via MFMA,
//   sliding 33-sum + fc2_b + relu, fc3, write out; also fill a-region with 1.0
// grid 256, 256 threads (4 waves), dynamic LDS 42624 B
__global__ __launch_bounds__(256) void k_fused(const float* __restrict__ x,
                                               const float* __restrict__ b1,
                                               const float* __restrict__ fc2b,
                                               const float* __restrict__ fc3w,
                                               const float* __restrict__ fc3b,
                                               const short* __restrict__ W1T,
                                               const short* __restrict__ WfT,
                                               float* __restrict__ out,
                                               float* __restrict__ aout) {
    extern __shared__ char smem[];
    short (*sA)[136]  = (short(*)[136])smem;            // 96x136 bf16: x then h1 (26112 B)
    float (*smv)[25]  = (float(*)[25])(smem + 26112);   // 96x25 f32 m  (9600 B)
    float (*sh2)[25]  = (float(*)[25])(smem + 35712);   // 64x25 f32 h2 (6400 B)
    float *sb1        = (float*)(smem + 42112);         // 128 f32      (512 B) -> 42624

    const int t = threadIdx.x, blk = blockIdx.x;
    const int g0 = blk * 64;                 // global row base
    const int bb = g0 >> 12;                 // batch index (g0 / 4096)
    const int l0 = g0 & (Lv - 1);            // in-batch row base
    const int lane = t & 63, w = t >> 6;

    // ---- stage x tile (rows l0-16 .. l0+79), bf16, zero outside [0,Lv)
    for (int i = t; i < 96*32; i += 256) {
        const int r = i >> 5, c4 = i & 31;
        const int l = l0 - 16 + r;
        short4v o = {0, 0, 0, 0};
        if (l >= 0 && l < Lv) {
            const float4 v = *(const float4*)&x[((size_t)bb*Lv + l)*Dv + c4*4];
            o[0] = f2bf(v.x); o[1] = f2bf(v.y); o[2] = f2bf(v.z); o[3] = f2bf(v.w);
        }
        *(short4v*)&sA[r][c4*4] = o;
    }
    if (t < Dv) sb1[t] = b1[t];
    __syncthreads();

    // ---- GEMM1: h1(96x128) = x(96x128) @ W1(128x128); wave w owns cols [w*32, w*32+32)
    const int ncol0 = w * 32;
    const int arow  = lane & 15;
    const int kgrp  = (lane >> 4) * 8;

    f32x4 acc[6][2];
#pragma unroll
    for (int mf = 0; mf < 6; ++mf) { acc[mf][0] = (f32x4){0,0,0,0}; acc[mf][1] = (f32x4){0,0,0,0}; }

#pragma unroll
    for (int kb = 0; kb < 4; ++kb) {
        const int kof = kb*32 + kgrp;
        const short8 bf0 = *(const short8*)&W1T[(size_t)(ncol0 +      arow)*Dv + kof];
        const short8 bf1 = *(const short8*)&W1T[(size_t)(ncol0 + 16 + arow)*Dv + kof];
#pragma unroll
        for (int mf = 0; mf < 6; ++mf) {
            const short8 af = *(const short8*)&sA[mf*16 + arow][kof];
            acc[mf][0] = __builtin_amdgcn_mfma_f32_16x16x32_bf16(af, bf0, acc[mf][0], 0, 0, 0);
            acc[mf][1] = __builtin_amdgcn_mfma_f32_16x16x32_bf16(af, bf1, acc[mf][1], 0, 0, 0);
        }
    }
    __syncthreads();   // all waves done reading sA(x)

    // ---- h1 = relu(acc + b1) -> sA as bf16
    // C/D layout: col = lane&15, row = (lane>>4)*4 + reg   [m89-verified]
    const int crow = (lane >> 4) * 4;
#pragma unroll
    for (int mf = 0; mf < 6; ++mf) {
#pragma unroll
        for (int nf = 0; nf < 2; ++nf) {
            const int col  = ncol0 + nf*16 + arow;
            const float bias = sb1[col];
#pragma unroll
            for (int r = 0; r < 4; ++r) {
                float h = acc[mf][nf][r] + bias;
                h = h > 0.f ? h : 0.f;
                sA[mf*16 + crow + r][col] = f2bf(h);
            }
        }
    }
    __syncthreads();

    // ---- GEMM2: m(96x24) = h1(96x128) @ Wf(128x24, padded to 32)
    // 12 (mf,nf) pairs, 3 per wave
    f32x4 acc2[3];
#pragma unroll
    for (int pp = 0; pp < 3; ++pp) acc2[pp] = (f32x4){0,0,0,0};
#pragma unroll
    for (int pp = 0; pp < 3; ++pp) {
        const int p = w*3 + pp, mf = p >> 1, nf = p & 1;
#pragma unroll
        for (int kb = 0; kb < 4; ++kb) {
            const int kof = kb*32 + kgrp;
            const short8 af = *(const short8*)&sA[mf*16 + arow][kof];
            const short8 bf = *(const short8*)&WfT[(size_t)(nf*16 + arow)*Dv + kof];
            acc2[pp] = __builtin_amdgcn_mfma_f32_16x16x32_bf16(af, bf, acc2[pp], 0, 0, 0);
        }
    }
    // write m -> smv (zero rows whose in-batch index is out of range)
#pragma unroll
    for (int pp = 0; pp < 3; ++pp) {
        const int p = w*3 + pp, mf = p >> 1, nf = p & 1;
        const int col = nf*16 + arow;
        if (col < HIDv) {
#pragma unroll
            for (int r = 0; r < 4; ++r) {
                const int row = mf*16 + crow + r;
                const int l = l0 - 16 + row;
                smv[row][col] = (l >= 0 && l < Lv) ? acc2[pp][r] : 0.f;
            }
        }
    }
    __syncthreads();

    // ---- sliding 33-sum + fc2_b + relu -> sh2 (running-sum per 16-row group)
    if (t < 96) {
        const int c = t % 24, rg = t / 24;
        const int rb = rg * 16;
        float s = 0.f;
#pragma unroll
        for (int ww = 0; ww < Wwin; ++ww) s += smv[rb + ww][c];
        const float bias = fc2b[c];
#pragma unroll
        for (int rr = 0; rr < 16; ++rr) {
            const float h = s + bias;
            sh2[rb + rr][c] = h > 0.f ? h : 0.f;
            if (rr < 15) s += smv[rb + rr + Wwin][c] - smv[rb + rr][c];
        }
    }
    __syncthreads();

    // ---- fc3: (64x24) @ (24x2) + b
    if (t < 128) {
        const int r = t >> 1, oc = t & 1;
        float a = fc3b[oc];
#pragma unroll
        for (int c = 0; c < HIDv; ++c)
            a = fmaf(sh2[r][c], fc3w[c*OUTv + oc], a);
        out[(size_t)(g0 + r)*OUTv + oc] = a;
    }

    // ---- attention weights = exactly 1.0 (softmax over size-1 axis)
    {
        float4* a4 = (float4*)aout;
        const float4 one4 = {1.f, 1.f, 1.f, 1.f};
        for (int i = t; i < 528; i += 256)          // 256 blocks x 528 = 135168 float4
            a4[(size_t)blk*528 + i] = one4;
    }
}

// ---------------------------------------------------------------------------
extern "C" void kernel_launch(void* const* d_in, const int* in_sizes, int n_in,
                              void* d_out, int out_size, void* d_ws, size_t ws_size,
                              hipStream_t stream) {
    const float* x     = (const float*)d_in[0];
    const float* fc1_w = (const float*)d_in[1];
    const float* fc1_b = (const float*)d_in[2];
    // d_in[3] = Wq_w, d_in[4] = Wk_w : dead (softmax over singleton axis)
    const float* Wv_w  = (const float*)d_in[5];
    const float* fc2_w = (const float*)d_in[6];
    const float* fc2_b = (const float*)d_in[7];
    const float* fc3_w = (const float*)d_in[8];
    const float* fc3_b = (const float*)d_in[9];

    float* out  = (float*)d_out;                    // (B,L,2)    32768 floats
    float* aout = (float*)d_out + NROWS * OUTv;     // (B,L,1,33) 540672 floats

    short* W1T = (short*)d_ws;                      // 128x128 bf16 (32768 B)
    short* WfT = (short*)d_ws + 16384;              // 32x128  bf16 (8192 B)

    k_prep<<<dim3(32), dim3(256), 0, stream>>>(fc1_w, Wv_w, fc2_w, W1T, WfT);
    k_fused<<<dim3(NROWS/64), dim3(256), 42624, stream>>>(x, fc1_b, fc2_b, fc3_w, fc3_b,
                                                          W1T, WfT, out, aout);
}

// Round 3
// 18.099 us; speedup vs baseline: 1.7293x; 1.1240x over previous
//
#include <hip/hip_runtime.h>

// Problem constants
constexpr int Bv   = 4;
constexpr int Lv   = 4096;
constexpr int Dv   = 128;
constexpr int Av   = 16;
constexpr int Wwin = 2*Av + 1;  // 33
constexpr int OUTv = 2;
constexpr int HIDv = 24;
constexpr int NROWS = Bv * Lv;  // 16384

constexpr int TILE  = 32;       // output rows per block
constexpr int SROWS = TILE + 2*Av;  // 64 staged rows
constexpr int NBLK  = NROWS / TILE; // 512

typedef __attribute__((ext_vector_type(8))) short short8;   // 8 bf16 (4 VGPR)
typedef __attribute__((ext_vector_type(4))) short short4v;  // 4 bf16 (8B)
typedef __attribute__((ext_vector_type(4))) float f32x4;    // MFMA acc

__device__ __forceinline__ short f2bf(float f) {  // RNE fp32->bf16
    unsigned u = __builtin_bit_cast(unsigned, f);
    u += 0x7FFFu + ((u >> 16) & 1u);
    return (short)(u >> 16);
}

// ---------------------------------------------------------------------------
// Prep: W1T[n][k] = fc1_w[k][n] as bf16 (128x128)   [blocks 0..15]
//       WfT[n][k] = sum_j Wv[k][j]*fc2[j][n] bf16 (32x128, rows 24..31 = 0)
//                                                    [blocks 16..31]
__global__ __launch_bounds__(256) void k_prep(const float* __restrict__ W1,
                                              const float* __restrict__ Wv,
                                              const float* __restrict__ fc2,
                                              short* __restrict__ W1T,
                                              short* __restrict__ WfT) {
    const int b = blockIdx.x, t = threadIdx.x;
    if (b < 16) {
        __shared__ float st[32][36];
        const int bi = b >> 2, bj = b & 3;      // tile (k-block, n-block)
        const int r = t >> 3, q = t & 7;
        const float4 v = *(const float4*)&W1[(size_t)(bi*32 + r)*Dv + bj*32 + q*4];
        st[r][q*4+0] = v.x; st[r][q*4+1] = v.y; st[r][q*4+2] = v.z; st[r][q*4+3] = v.w;
        __syncthreads();
        short4v o;
        o[0] = f2bf(st[q*4+0][r]);
        o[1] = f2bf(st[q*4+1][r]);
        o[2] = f2bf(st[q*4+2][r]);
        o[3] = f2bf(st[q*4+3][r]);
        *(short4v*)&W1T[(size_t)(bj*32 + r)*Dv + bi*32 + q*4] = o;
    } else {
        // lane-coalesced mapping: n = i&31 (lane-varying), k = i>>5 (wave-uniform-ish)
        const int i = (b - 16)*256 + t;         // 0..4095
        const int n = i & 31, k = i >> 5;
        float acc = 0.f;
        if (n < HIDv) {
#pragma unroll 8
            for (int j = 0; j < Dv; ++j)
                acc = fmaf(Wv[(size_t)k*Dv + j], fc2[(size_t)j*HIDv + n], acc);
        }
        WfT[(size_t)n*Dv + k] = f2bf(acc);
    }
}

// ---------------------------------------------------------------------------
// Fused: per block = 32 output rows (+16 halo each side -> 64 staged)
//   h1 = relu(x@W1+b1) via MFMA (64 rows), m = h1@Wf via MFMA,
//   sliding 33-sum + fc2_b + relu, fc3 -> out; also fill a-region with 1.0
// grid 512, 256 threads (4 waves), static LDS ~27.5 KB -> 2 blocks/CU
__global__ __launch_bounds__(256) void k_fused(const float* __restrict__ x,
                                               const float* __restrict__ b1,
                                               const float* __restrict__ fc2b,
                                               const float* __restrict__ fc3w,
                                               const float* __restrict__ fc3b,
                                               const short* __restrict__ W1T,
                                               const short* __restrict__ WfT,
                                               float* __restrict__ out,
                                               float* __restrict__ aout) {
    __shared__ short sA[SROWS][136];    // x then h1, bf16 (17408 B)
    __shared__ float smv[SROWS][25];    // m, f32 (6400 B)
    __shared__ float sh2[TILE][25];     // h2, f32 (3200 B)
    __shared__ float sb1[Dv];           // 512 B

    const int t = threadIdx.x, blk = blockIdx.x;
    const int g0 = blk * TILE;               // global output row base
    const int bb = g0 >> 12;                 // batch index
    const int l0 = g0 & (Lv - 1);            // in-batch row base
    const int lane = t & 63, w = t >> 6;

    // ---- stage x tile (rows l0-16 .. l0+47), bf16, zero outside [0,Lv)
    for (int i = t; i < SROWS*32; i += 256) {
        const int r = i >> 5, c4 = i & 31;
        const int l = l0 - Av + r;
        short4v o = {0, 0, 0, 0};
        if (l >= 0 && l < Lv) {
            const float4 v = *(const float4*)&x[((size_t)bb*Lv + l)*Dv + c4*4];
            o[0] = f2bf(v.x); o[1] = f2bf(v.y); o[2] = f2bf(v.z); o[3] = f2bf(v.w);
        }
        *(short4v*)&sA[r][c4*4] = o;
    }
    if (t < Dv) sb1[t] = b1[t];

    // ---- attention weights = 1.0 (independent; overlap with compute)
    {
        float4* a4 = (float4*)aout;
        const float4 one4 = {1.f, 1.f, 1.f, 1.f};
        for (int i = t; i < 264; i += 256)       // 512 blocks x 264 = 135168 float4
            a4[(size_t)blk*264 + i] = one4;
    }
    __syncthreads();

    // ---- GEMM1: h1(64x128) = x(64x128) @ W1(128x128); wave w owns cols [w*32, w*32+32)
    const int ncol0 = w * 32;
    const int arow  = lane & 15;
    const int kgrp  = (lane >> 4) * 8;

    f32x4 acc[4][2];
#pragma unroll
    for (int mf = 0; mf < 4; ++mf) { acc[mf][0] = (f32x4){0,0,0,0}; acc[mf][1] = (f32x4){0,0,0,0}; }

#pragma unroll
    for (int kb = 0; kb < 4; ++kb) {
        const int kof = kb*32 + kgrp;
        const short8 bf0 = *(const short8*)&W1T[(size_t)(ncol0 +      arow)*Dv + kof];
        const short8 bf1 = *(const short8*)&W1T[(size_t)(ncol0 + 16 + arow)*Dv + kof];
#pragma unroll
        for (int mf = 0; mf < 4; ++mf) {
            const short8 af = *(const short8*)&sA[mf*16 + arow][kof];
            acc[mf][0] = __builtin_amdgcn_mfma_f32_16x16x32_bf16(af, bf0, acc[mf][0], 0, 0, 0);
            acc[mf][1] = __builtin_amdgcn_mfma_f32_16x16x32_bf16(af, bf1, acc[mf][1], 0, 0, 0);
        }
    }
    __syncthreads();   // all waves done reading sA(x)

    // ---- h1 = relu(acc + b1) -> sA as bf16
    // C/D layout: col = lane&15, row = (lane>>4)*4 + reg   [m89-verified]
    const int crow = (lane >> 4) * 4;
#pragma unroll
    for (int mf = 0; mf < 4; ++mf) {
#pragma unroll
        for (int nf = 0; nf < 2; ++nf) {
            const int col  = ncol0 + nf*16 + arow;
            const float bias = sb1[col];
#pragma unroll
            for (int r = 0; r < 4; ++r) {
                float h = acc[mf][nf][r] + bias;
                h = h > 0.f ? h : 0.f;
                sA[mf*16 + crow + r][col] = f2bf(h);
            }
        }
    }
    __syncthreads();

    // ---- GEMM2: m(64x24) = h1(64x128) @ Wf(128x24 padded 32)
    // 8 (mf,nf) pairs, 2 per wave
    f32x4 acc2[2];
    acc2[0] = (f32x4){0,0,0,0};
    acc2[1] = (f32x4){0,0,0,0};
#pragma unroll
    for (int pp = 0; pp < 2; ++pp) {
        const int p = w*2 + pp, mf = p >> 1, nf = p & 1;
#pragma unroll
        for (int kb = 0; kb < 4; ++kb) {
            const int kof = kb*32 + kgrp;
            const short8 af = *(const short8*)&sA[mf*16 + arow][kof];
            const short8 bf = *(const short8*)&WfT[(size_t)(nf*16 + arow)*Dv + kof];
            acc2[pp] = __builtin_amdgcn_mfma_f32_16x16x32_bf16(af, bf, acc2[pp], 0, 0, 0);
        }
    }
    // write m -> smv (zero rows whose in-batch index is out of range)
#pragma unroll
    for (int pp = 0; pp < 2; ++pp) {
        const int p = w*2 + pp, mf = p >> 1, nf = p & 1;
        const int col = nf*16 + arow;
        if (col < HIDv) {
#pragma unroll
            for (int r = 0; r < 4; ++r) {
                const int row = mf*16 + crow + r;
                const int l = l0 - Av + row;
                smv[row][col] = (l >= 0 && l < Lv) ? acc2[pp][r] : 0.f;
            }
        }
    }
    __syncthreads();

    // ---- sliding 33-sum + fc2_b + relu -> sh2 (running-sum, 8-row groups)
    if (t < 96) {
        const int c = t % 24, rg = t / 24;
        const int rb = rg * 8;
        float s = 0.f;
#pragma unroll
        for (int ww = 0; ww < Wwin; ++ww) s += smv[rb + ww][c];
        const float bias = fc2b[c];
#pragma unroll
        for (int r2 = 0; r2 < 8; ++r2) {
            const int rr = rb + r2;
            const float h = s + bias;
            sh2[rr][c] = h > 0.f ? h : 0.f;
            if (r2 < 7) s += smv[rr + Wwin][c] - smv[rr][c];
        }
    }
    __syncthreads();

    // ---- fc3: (32x24) @ (24x2) + b
    if (t < TILE*OUTv) {
        const int r = t >> 1, oc = t & 1;
        float a = fc3b[oc];
#pragma unroll
        for (int c = 0; c < HIDv; ++c)
            a = fmaf(sh2[r][c], fc3w[c*OUTv + oc], a);
        out[(size_t)(g0 + r)*OUTv + oc] = a;
    }
}

// ---------------------------------------------------------------------------
extern "C" void kernel_launch(void* const* d_in, const int* in_sizes, int n_in,
                              void* d_out, int out_size, void* d_ws, size_t ws_size,
                              hipStream_t stream) {
    const float* x     = (const float*)d_in[0];
    const float* fc1_w = (const float*)d_in[1];
    const float* fc1_b = (const float*)d_in[2];
    // d_in[3] = Wq_w, d_in[4] = Wk_w : dead (softmax over singleton axis)
    const float* Wv_w  = (const float*)d_in[5];
    const float* fc2_w = (const float*)d_in[6];
    const float* fc2_b = (const float*)d_in[7];
    const float* fc3_w = (const float*)d_in[8];
    const float* fc3_b = (const float*)d_in[9];

    float* out  = (float*)d_out;                    // (B,L,2)    32768 floats
    float* aout = (float*)d_out + NROWS * OUTv;     // (B,L,1,33) 540672 floats

    short* W1T = (short*)d_ws;                      // 128x128 bf16 (32768 B)
    short* WfT = (short*)d_ws + 16384;              // 32x128  bf16 (8192 B)

    k_prep<<<dim3(32), dim3(256), 0, stream>>>(fc1_w, Wv_w, fc2_w, W1T, WfT);
    k_fused<<<dim3(NBLK), dim3(256), 0, stream>>>(x, fc1_b, fc2_b, fc3_w, fc3_b,
                                                  W1T, WfT, out, aout);
}

// Round 4
// 16.387 us; speedup vs baseline: 1.9098x; 1.1044x over previous
//
#include <hip/hip_runtime.h>

// Problem constants
constexpr int Bv   = 4;
constexpr int Lv   = 4096;
constexpr int Dv   = 128;
constexpr int Av   = 16;
constexpr int Wwin = 2*Av + 1;  // 33
constexpr int OUTv = 2;
constexpr int HIDv = 24;
constexpr int NROWS = Bv * Lv;  // 16384

constexpr int TILE  = 32;           // output rows per block
constexpr int SROWS = TILE + 2*Av;  // 64 staged rows
constexpr int NBLK  = NROWS / TILE; // 512

typedef __attribute__((ext_vector_type(8))) short short8;   // 8 bf16 (4 VGPR)
typedef __attribute__((ext_vector_type(4))) short short4v;  // 4 bf16 (8B)
typedef __attribute__((ext_vector_type(4))) float f32x4;    // MFMA acc

__device__ __forceinline__ short f2bf(float f) {  // RNE fp32->bf16
    unsigned u = __builtin_bit_cast(unsigned, f);
    u += 0x7FFFu + ((u >> 16) & 1u);
    return (short)(u >> 16);
}

// ---------------------------------------------------------------------------
// Single fused kernel: per block = 32 output rows (+16 halo each side).
//   Wf = Wv@fc2 per-block via MFMA (redundant, weights L2-resident)
//   h1 = relu(x@W1+b1) via MFMA with on-the-fly B-frags from fp32 W1
//   m  = h1@Wf via MFMA; sliding 33-sum + fc2_b + relu; fc3 -> out
//   a-output = 1.0 (softmax over size-1 axis)
// grid 512, 256 threads (4 waves), LDS ~36.2 KB -> 2 blocks/CU
__global__ __launch_bounds__(256) void k_all(const float* __restrict__ x,
                                             const float* __restrict__ W1,
                                             const float* __restrict__ b1,
                                             const float* __restrict__ Wv,
                                             const float* __restrict__ fc2,
                                             const float* __restrict__ fc2b,
                                             const float* __restrict__ fc3w,
                                             const float* __restrict__ fc3b,
                                             float* __restrict__ out,
                                             float* __restrict__ aout) {
    __shared__ short sA[SROWS][136];    // x then h1, bf16 (17408 B)
    __shared__ short sWfT[32][136];     // Wf^T bf16      (8704 B)
    __shared__ float smv[SROWS][25];    // m, f32         (6400 B)
    __shared__ float sh2[TILE][25];     // h2, f32        (3200 B)
    __shared__ float sb1[Dv];           // 512 B

    const int t = threadIdx.x, blk = blockIdx.x;
    const int g0 = blk * TILE;               // global output row base
    const int bb = g0 >> 12;                 // batch index
    const int l0 = g0 & (Lv - 1);            // in-batch row base
    const int lane = t & 63, w = t >> 6;
    const int arow = lane & 15;
    const int kgrp = (lane >> 4) * 8;
    const int crow = (lane >> 4) * 4;

    // ---- phase 1: stage x tile (rows l0-16 .. l0+47), bf16, zero outside [0,Lv)
    for (int i = t; i < SROWS*32; i += 256) {
        const int r = i >> 5, c4 = i & 31;
        const int l = l0 - Av + r;
        short4v o = {0, 0, 0, 0};
        if (l >= 0 && l < Lv) {
            const float4 v = *(const float4*)&x[((size_t)bb*Lv + l)*Dv + c4*4];
            o[0] = f2bf(v.x); o[1] = f2bf(v.y); o[2] = f2bf(v.z); o[3] = f2bf(v.w);
        }
        *(short4v*)&sA[r][c4*4] = o;
    }
    if (t < Dv) sb1[t] = b1[t];

    // ---- attention weights = 1.0 (independent; overlaps with loads)
    {
        float4* a4 = (float4*)aout;
        const float4 one4 = {1.f, 1.f, 1.f, 1.f};
        for (int i = t; i < 264; i += 256)       // 512 blocks x 264 = 135168 float4
            a4[(size_t)blk*264 + i] = one4;
    }

    // ---- phase 2: Wf = Wv @ fc2 via MFMA (per-block redundant)
    // wave w owns output rows mf in {2w, 2w+1} (x16), cols nf in {0,1} (x16)
    {
        f32x4 accW[2][2];
#pragma unroll
        for (int a = 0; a < 2; ++a) { accW[a][0] = (f32x4){0,0,0,0}; accW[a][1] = (f32x4){0,0,0,0}; }
#pragma unroll
        for (int kb = 0; kb < 4; ++kb) {
            const int kof = kb*32 + kgrp;
            short8 bW[2];
#pragma unroll
            for (int nf = 0; nf < 2; ++nf) {
                const int n = nf*16 + arow;
#pragma unroll
                for (int j = 0; j < 8; ++j) {
                    const float v = (n < HIDv) ? fc2[(size_t)(kof + j)*HIDv + n] : 0.f;
                    bW[nf][j] = f2bf(v);
                }
            }
#pragma unroll
            for (int mf2 = 0; mf2 < 2; ++mf2) {
                const int m = (w*2 + mf2)*16 + arow;
                const float4 v0 = *(const float4*)&Wv[(size_t)m*Dv + kof];
                const float4 v1 = *(const float4*)&Wv[(size_t)m*Dv + kof + 4];
                short8 aW;
                aW[0] = f2bf(v0.x); aW[1] = f2bf(v0.y); aW[2] = f2bf(v0.z); aW[3] = f2bf(v0.w);
                aW[4] = f2bf(v1.x); aW[5] = f2bf(v1.y); aW[6] = f2bf(v1.z); aW[7] = f2bf(v1.w);
                accW[mf2][0] = __builtin_amdgcn_mfma_f32_16x16x32_bf16(aW, bW[0], accW[mf2][0], 0, 0, 0);
                accW[mf2][1] = __builtin_amdgcn_mfma_f32_16x16x32_bf16(aW, bW[1], accW[mf2][1], 0, 0, 0);
            }
        }
        // write Wf^T to LDS: C-frag val = Wf[(w*2+mf2)*16 + crow + r][nf*16 + arow]
#pragma unroll
        for (int mf2 = 0; mf2 < 2; ++mf2) {
#pragma unroll
            for (int nf = 0; nf < 2; ++nf) {
                const int n = nf*16 + arow;
                const int m = (w*2 + mf2)*16 + crow;
                short4v o;
                o[0] = f2bf(accW[mf2][nf][0]);
                o[1] = f2bf(accW[mf2][nf][1]);
                o[2] = f2bf(accW[mf2][nf][2]);
                o[3] = f2bf(accW[mf2][nf][3]);
                *(short4v*)&sWfT[n][m] = o;
            }
        }
    }
    __syncthreads();   // publish sA (x) + sWfT

    // ---- phase 3: GEMM1  h1(64x128) = x @ W1 ; wave w owns cols [w*32, w*32+32)
    const int ncol0 = w * 32;
    f32x4 acc[4][2];
#pragma unroll
    for (int mf = 0; mf < 4; ++mf) { acc[mf][0] = (f32x4){0,0,0,0}; acc[mf][1] = (f32x4){0,0,0,0}; }

#pragma unroll
    for (int kb = 0; kb < 4; ++kb) {
        const int kof = kb*32 + kgrp;
        // B-frags on the fly from fp32 W1 (L2-resident): bf[j] = W1[kof+j][ncol]
        short8 bf0, bf1;
        {
            const int n0 = ncol0 + arow, n1 = ncol0 + 16 + arow;
#pragma unroll
            for (int j = 0; j < 8; ++j) {
                bf0[j] = f2bf(W1[(size_t)(kof + j)*Dv + n0]);
                bf1[j] = f2bf(W1[(size_t)(kof + j)*Dv + n1]);
            }
        }
#pragma unroll
        for (int mf = 0; mf < 4; ++mf) {
            const short8 af = *(const short8*)&sA[mf*16 + arow][kof];
            acc[mf][0] = __builtin_amdgcn_mfma_f32_16x16x32_bf16(af, bf0, acc[mf][0], 0, 0, 0);
            acc[mf][1] = __builtin_amdgcn_mfma_f32_16x16x32_bf16(af, bf1, acc[mf][1], 0, 0, 0);
        }
    }
    __syncthreads();   // all waves done reading sA (x)

    // ---- phase 4: h1 = relu(acc + b1) -> sA as bf16
    // C/D layout: col = lane&15, row = (lane>>4)*4 + reg   [m89-verified]
#pragma unroll
    for (int mf = 0; mf < 4; ++mf) {
#pragma unroll
        for (int nf = 0; nf < 2; ++nf) {
            const int col  = ncol0 + nf*16 + arow;
            const float bias = sb1[col];
#pragma unroll
            for (int r = 0; r < 4; ++r) {
                float h = acc[mf][nf][r] + bias;
                h = h > 0.f ? h : 0.f;
                sA[mf*16 + crow + r][col] = f2bf(h);
            }
        }
    }
    __syncthreads();

    // ---- phase 5: GEMM2  m(64x24) = h1 @ Wf (128x24 padded 32); 2 (mf,nf) pairs/wave
    f32x4 acc2[2];
    acc2[0] = (f32x4){0,0,0,0};
    acc2[1] = (f32x4){0,0,0,0};
#pragma unroll
    for (int pp = 0; pp < 2; ++pp) {
        const int p = w*2 + pp, mf = p >> 1, nf = p & 1;
#pragma unroll
        for (int kb = 0; kb < 4; ++kb) {
            const int kof = kb*32 + kgrp;
            const short8 af = *(const short8*)&sA[mf*16 + arow][kof];
            const short8 bf = *(const short8*)&sWfT[nf*16 + arow][kof];
            acc2[pp] = __builtin_amdgcn_mfma_f32_16x16x32_bf16(af, bf, acc2[pp], 0, 0, 0);
        }
    }
    // write m -> smv (zero rows whose in-batch index is out of range)
#pragma unroll
    for (int pp = 0; pp < 2; ++pp) {
        const int p = w*2 + pp, mf = p >> 1, nf = p & 1;
        const int col = nf*16 + arow;
        if (col < HIDv) {
#pragma unroll
            for (int r = 0; r < 4; ++r) {
                const int row = mf*16 + crow + r;
                const int l = l0 - Av + row;
                smv[row][col] = (l >= 0 && l < Lv) ? acc2[pp][r] : 0.f;
            }
        }
    }
    __syncthreads();

    // ---- phase 6: sliding 33-sum + fc2_b + relu -> sh2 (running-sum, 8-row groups)
    if (t < 96) {
        const int c = t % 24, rg = t / 24;
        const int rb = rg * 8;
        float s = 0.f;
#pragma unroll
        for (int ww = 0; ww < Wwin; ++ww) s += smv[rb + ww][c];
        const float bias = fc2b[c];
#pragma unroll
        for (int r2 = 0; r2 < 8; ++r2) {
            const int rr = rb + r2;
            const float h = s + bias;
            sh2[rr][c] = h > 0.f ? h : 0.f;
            if (r2 < 7) s += smv[rr + Wwin][c] - smv[rr][c];
        }
    }
    __syncthreads();

    // ---- phase 7: fc3 (32x24)@(24x2) + b -> out
    if (t < TILE*OUTv) {
        const int r = t >> 1, oc = t & 1;
        float a = fc3b[oc];
#pragma unroll
        for (int c = 0; c < HIDv; ++c)
            a = fmaf(sh2[r][c], fc3w[c*OUTv + oc], a);
        out[(size_t)(g0 + r)*OUTv + oc] = a;
    }
}

// ---------------------------------------------------------------------------
extern "C" void kernel_launch(void* const* d_in, const int* in_sizes, int n_in,
                              void* d_out, int out_size, void* d_ws, size_t ws_size,
                              hipStream_t stream) {
    const float* x     = (const float*)d_in[0];
    const float* fc1_w = (const float*)d_in[1];
    const float* fc1_b = (const float*)d_in[2];
    // d_in[3] = Wq_w, d_in[4] = Wk_w : dead (softmax over singleton axis)
    const float* Wv_w  = (const float*)d_in[5];
    const float* fc2_w = (const float*)d_in[6];
    const float* fc2_b = (const float*)d_in[7];
    const float* fc3_w = (const float*)d_in[8];
    const float* fc3_b = (const float*)d_in[9];

    float* out  = (float*)d_out;                    // (B,L,2)    32768 floats
    float* aout = (float*)d_out + NROWS * OUTv;     // (B,L,1,33) 540672 floats

    k_all<<<dim3(NBLK), dim3(256), 0, stream>>>(x, fc1_w, fc1_b, Wv_w, fc2_w,
                                                fc2_b, fc3_w, fc3_b, out, aout);
}